// Round 1
// baseline (1310.650 us; speedup 1.0000x reference)
//
#include <hip/hip_runtime.h>
#include <hip/hip_bf16.h>

typedef _Float16 f16;
typedef __attribute__((ext_vector_type(8))) _Float16 f16x8;
typedef __attribute__((ext_vector_type(4))) _Float16 f16x4;
typedef __attribute__((ext_vector_type(4))) float f32x4;

#define DIM 1024
#define HEADS 16
#define DHEAD 64
#define MLPD 4096
#define NQ 16384
#define NW 1024

// ---------------- async global->LDS (16B per lane) ----------------
__device__ __forceinline__ void glds16(const f16* g, f16* l) {
  __builtin_amdgcn_global_load_lds(
      (const __attribute__((address_space(1))) void*)g,
      (__attribute__((address_space(3))) void*)l, 16, 0, 0);
}

// ---------------- LayerNorm(1024) -> f16 ----------------
__global__ __launch_bounds__(256) void ln_f16_k(
    const float* __restrict__ X, const float* __restrict__ w,
    const float* __restrict__ b, f16* __restrict__ O) {
  const int row = blockIdx.x;
  const int t = threadIdx.x;
  const float4 v = ((const float4*)(X + (long)row * DIM))[t];
  float s = v.x + v.y + v.z + v.w;
  float s2 = v.x * v.x + v.y * v.y + v.z * v.z + v.w * v.w;
#pragma unroll
  for (int m = 1; m < 64; m <<= 1) {
    s += __shfl_xor(s, m);
    s2 += __shfl_xor(s2, m);
  }
  __shared__ float ps[4], ps2[4];
  const int lane = t & 63, wid = t >> 6;
  if (lane == 0) { ps[wid] = s; ps2[wid] = s2; }
  __syncthreads();
  s = ps[0] + ps[1] + ps[2] + ps[3];
  s2 = ps2[0] + ps2[1] + ps2[2] + ps2[3];
  const float mu = s * (1.0f / DIM);
  const float inv = rsqrtf(s2 * (1.0f / DIM) - mu * mu + 1e-5f);
  const float4 wv = ((const float4*)w)[t];
  const float4 bv = ((const float4*)b)[t];
  f16x4 o;
  o[0] = (f16)((v.x - mu) * inv * wv.x + bv.x);
  o[1] = (f16)((v.y - mu) * inv * wv.y + bv.y);
  o[2] = (f16)((v.z - mu) * inv * wv.z + bv.z);
  o[3] = (f16)((v.w - mu) * inv * wv.w + bv.w);
  *(f16x4*)(O + (long)row * DIM + t * 4) = o;
}

// ---------------- transpose + cast f32[R][C] -> f16[C][R] ----------------
__global__ __launch_bounds__(256) void tcast_k(const float* __restrict__ X,
                                               f16* __restrict__ O, int R, int C) {
  __shared__ float tile[32][33];
  const int c0 = blockIdx.x * 32, r0 = blockIdx.y * 32;
  const int tx = threadIdx.x, ty = threadIdx.y;  // (32,8)
#pragma unroll
  for (int j = 0; j < 4; ++j)
    tile[ty + j * 8][tx] = X[(long)(r0 + ty + j * 8) * C + c0 + tx];
  __syncthreads();
#pragma unroll
  for (int j = 0; j < 4; ++j)
    O[(long)(c0 + ty + j * 8) * R + r0 + tx] = (f16)tile[tx][ty + j * 8];
}

// ---------------- M_h = khat_h^T @ v_h  (64x64 per head, K=1024) ----------------
__global__ __launch_bounds__(256) void calc_m_k(const f16* __restrict__ kh,
                                                const f16* __restrict__ v,
                                                float* __restrict__ Mo) {
  const int h = blockIdx.x;
  const int t = threadIdx.x;
  const int d1 = t >> 2;
  const int d2b = (t & 3) * 16;
  float acc[16] = {};
  for (int n = 0; n < NW; ++n) {
    const float kv = (float)kh[(long)n * DIM + h * DHEAD + d1];
    const f16x8* vp = (const f16x8*)&v[(long)n * DIM + h * DHEAD + d2b];
    const f16x8 v0 = vp[0], v1 = vp[1];
#pragma unroll
    for (int j = 0; j < 8; ++j) acc[j] += kv * (float)v0[j];
#pragma unroll
    for (int j = 0; j < 8; ++j) acc[8 + j] += kv * (float)v1[j];
  }
#pragma unroll
  for (int j = 0; j < 16; ++j)
    Mo[h * 4096 + d1 * 64 + d2b + j] = acc[j];
}

// ---------------- W_eff^T[j][i] = sum_d M[h(i)][i%64][d] * wo[h*64+d][j] ----------------
__global__ __launch_bounds__(256) void calc_wefft_k(const float* __restrict__ M,
                                                    const float* __restrict__ wo,
                                                    f16* __restrict__ Wt) {
  const int h = blockIdx.x, jt = blockIdx.y;
  const int t = threadIdx.x;
  const int jl = t & 63;
  const int il0 = (t >> 6) * 16;
  const int j = jt * 64 + jl;
  float acc[16] = {};
  for (int d = 0; d < DHEAD; ++d) {
    const float w = wo[(long)(h * DHEAD + d) * DIM + j];
    const float* mrow = &M[h * 4096 + il0 * 64 + d];
#pragma unroll
    for (int r = 0; r < 16; ++r) acc[r] += mrow[r * 64] * w;
  }
#pragma unroll
  for (int r = 0; r < 16; ++r)
    Wt[(long)j * DIM + h * DHEAD + il0 + r] = (f16)acc[r];
}

// ---------------- main GEMM: C[M][N] = A[M][K](f16) @ Bt[N][K](f16)^T + epilogue ----------
// 128x128 tile, BK=32, 256 threads = 4 waves (2x2), mfma_f32_16x16x32_f16.
enum { EPI_F16 = 0, EPI_L2N = 1, EPI_BIAS_RES = 2, EPI_GELU = 3 };

template <int EPI>
__global__ __launch_bounds__(256, 2) void gemm_f16(
    const f16* __restrict__ A, const f16* __restrict__ Bt, int M, int N, int K,
    const float* __restrict__ bias, const float* __restrict__ resid,
    void* __restrict__ out) {
  __shared__ __align__(16) f16 As[128 * 32];
  __shared__ __align__(16) f16 Bs[128 * 32];

  const int tid = threadIdx.x;
  const int lane = tid & 63;
  const int bm = blockIdx.x, bn = blockIdx.y;
  const int wid = tid >> 6;
  const int wh = wid >> 1, ww = wid & 1;

  // staging: thread t loads 8 f16 at row=t/4 (+64 for 2nd half), k=(t%4)*8
  const int srow = tid >> 2;
  const int sk = (tid & 3) * 8;
  const f16* ag = A + (long)(bm * 128 + srow) * K + sk;
  const f16* bg = Bt + (long)(bn * 128 + srow) * K + sk;
  f16* asd = &As[tid * 8];
  f16* bsd = &Bs[tid * 8];
  const long hstep = (long)64 * K;

  f32x4 acc[4][4] = {};
  const int nk = K >> 5;
  for (int kt = 0; kt < nk; ++kt) {
    if (kt) __syncthreads();
    const long go = (long)kt * 32;
    glds16(ag + go, asd);
    glds16(ag + hstep + go, asd + 2048);
    glds16(bg + go, bsd);
    glds16(bg + hstep + go, bsd + 2048);
    __syncthreads();

    f16x8 af[4], bf[4];
    const int ar = wh * 64 + (lane & 15);
    const int br = ww * 64 + (lane & 15);
    const int ko = (lane >> 4) * 8;
#pragma unroll
    for (int mi = 0; mi < 4; ++mi)
      af[mi] = *(const f16x8*)&As[(ar + mi * 16) * 32 + ko];
#pragma unroll
    for (int nj = 0; nj < 4; ++nj)
      bf[nj] = *(const f16x8*)&Bs[(br + nj * 16) * 32 + ko];
#pragma unroll
    for (int mi = 0; mi < 4; ++mi)
#pragma unroll
      for (int nj = 0; nj < 4; ++nj)
        acc[mi][nj] = __builtin_amdgcn_mfma_f32_16x16x32_f16(af[mi], bf[nj],
                                                             acc[mi][nj], 0, 0, 0);
  }

  // epilogue: D row=(lane>>4)*4+i, col=lane&15 within each 16x16 frag
  const int r0 = bm * 128 + wh * 64;
  const int c0 = bn * 128 + ww * 64;
  const int lr = (lane >> 4) * 4;
  const int lc = lane & 15;

#pragma unroll
  for (int mi = 0; mi < 4; ++mi) {
#pragma unroll
    for (int i = 0; i < 4; ++i) {
      const long r = r0 + mi * 16 + lr + i;
      if (EPI == EPI_L2N) {
        // wave's 64 cols == one head: l2-normalize this output row over the head
        float ss = 0.f;
#pragma unroll
        for (int nj = 0; nj < 4; ++nj) {
          const float x = acc[mi][nj][i];
          ss += x * x;
        }
        ss += __shfl_xor(ss, 1);
        ss += __shfl_xor(ss, 2);
        ss += __shfl_xor(ss, 4);
        ss += __shfl_xor(ss, 8);
        const float inv = 1.0f / fmaxf(sqrtf(ss), 1e-12f);
#pragma unroll
        for (int nj = 0; nj < 4; ++nj)
          ((f16*)out)[r * N + c0 + nj * 16 + lc] = (f16)(acc[mi][nj][i] * inv);
      } else if (EPI == EPI_F16) {
#pragma unroll
        for (int nj = 0; nj < 4; ++nj)
          ((f16*)out)[r * N + c0 + nj * 16 + lc] = (f16)acc[mi][nj][i];
      } else if (EPI == EPI_BIAS_RES) {
#pragma unroll
        for (int nj = 0; nj < 4; ++nj) {
          const long c = c0 + nj * 16 + lc;
          ((float*)out)[r * N + c] = acc[mi][nj][i] + bias[c] + resid[r * N + c];
        }
      } else {  // EPI_GELU (exact erf)
#pragma unroll
        for (int nj = 0; nj < 4; ++nj) {
          const long c = c0 + nj * 16 + lc;
          const float x = acc[mi][nj][i] + bias[c];
          ((f16*)out)[r * N + c] =
              (f16)(0.5f * x * (1.0f + erff(x * 0.70710678118654752f)));
        }
      }
    }
  }
}

extern "C" void kernel_launch(void* const* d_in, const int* in_sizes, int n_in,
                              void* d_out, int out_size, void* d_ws, size_t ws_size,
                              hipStream_t stream) {
  (void)in_sizes; (void)n_in; (void)out_size;
  const float* queries = (const float*)d_in[0];
  const float* prototypes = (const float*)d_in[1];
  const float* ln1_w = (const float*)d_in[2];
  const float* ln1_b = (const float*)d_in[3];
  const float* wq = (const float*)d_in[4];
  const float* wk = (const float*)d_in[5];
  const float* wv = (const float*)d_in[6];
  const float* wo = (const float*)d_in[7];
  const float* bo = (const float*)d_in[8];
  const float* ln2_w = (const float*)d_in[9];
  const float* ln2_b = (const float*)d_in[10];
  const float* w1 = (const float*)d_in[11];
  const float* b1 = (const float*)d_in[12];
  const float* w2 = (const float*)d_in[13];
  const float* b2 = (const float*)d_in[14];

  char* ws = (char*)d_ws;
  const size_t MB = 1024ull * 1024ull;
  if (ws_size < 192ull * MB) return;  // workspace layout needs 192MB

  // transient region (all dead before MLP; G aliases QN)
  f16* QN = (f16*)(ws + 0);           // 32MB  [16384][1024]
  f16* QHAT = (f16*)(ws + 32 * MB);   // 32MB
  f16* PN = (f16*)(ws + 64 * MB);     // 2MB
  f16* WQT = (f16*)(ws + 66 * MB);    // 2MB
  f16* WKT = (f16*)(ws + 68 * MB);    // 2MB
  f16* WVT = (f16*)(ws + 70 * MB);    // 2MB
  f16* KHAT = (f16*)(ws + 72 * MB);   // 2MB
  f16* VBF = (f16*)(ws + 74 * MB);    // 2MB
  float* Mbuf = (float*)(ws + 76 * MB);  // 256KB
  f16* WEFFT = (f16*)(ws + 77 * MB);  // 2MB
  // persistent region
  float* RES2 = (float*)(ws + 80 * MB);  // 64MB
  f16* HBF = (f16*)(ws + 144 * MB);      // 32MB
  f16* W1T = (f16*)(ws + 176 * MB);      // 8MB [4096][1024]
  f16* W2T = (f16*)(ws + 184 * MB);      // 8MB [1024][4096]
  f16* G = (f16*)(ws + 0);               // 32MB chunk buffer [4096][4096], aliases QN

  // LN1 + cast
  ln_f16_k<<<NQ, 256, 0, stream>>>(queries, ln1_w, ln1_b, QN);
  ln_f16_k<<<NW, 256, 0, stream>>>(prototypes, ln1_w, ln1_b, PN);
  // weight transpose-casts
  tcast_k<<<dim3(32, 32), dim3(32, 8), 0, stream>>>(wq, WQT, DIM, DIM);
  tcast_k<<<dim3(32, 32), dim3(32, 8), 0, stream>>>(wk, WKT, DIM, DIM);
  tcast_k<<<dim3(32, 32), dim3(32, 8), 0, stream>>>(wv, WVT, DIM, DIM);
  tcast_k<<<dim3(128, 32), dim3(32, 8), 0, stream>>>(w1, W1T, DIM, MLPD);
  tcast_k<<<dim3(32, 128), dim3(32, 8), 0, stream>>>(w2, W2T, MLPD, DIM);

  // projections (+fused per-head l2norm for q,k)
  gemm_f16<EPI_L2N><<<dim3(NQ / 128, DIM / 128), 256, 0, stream>>>(
      QN, WQT, NQ, DIM, DIM, nullptr, nullptr, QHAT);
  gemm_f16<EPI_L2N><<<dim3(NW / 128, DIM / 128), 256, 0, stream>>>(
      PN, WKT, NW, DIM, DIM, nullptr, nullptr, KHAT);
  gemm_f16<EPI_F16><<<dim3(NW / 128, DIM / 128), 256, 0, stream>>>(
      PN, WVT, NW, DIM, DIM, nullptr, nullptr, VBF);

  // attention collapse: M_h = khat^T v ; W_eff^T = (blockdiag(M) @ wo)^T
  calc_m_k<<<HEADS, 256, 0, stream>>>(KHAT, VBF, Mbuf);
  calc_wefft_k<<<dim3(HEADS, 16), 256, 0, stream>>>(Mbuf, wo, WEFFT);

  // attn-out + wo + bias + residual -> RES2 (f32)
  gemm_f16<EPI_BIAS_RES><<<dim3(NQ / 128, DIM / 128), 256, 0, stream>>>(
      QHAT, WEFFT, NQ, DIM, DIM, bo, queries, RES2);

  // LN2
  ln_f16_k<<<NQ, 256, 0, stream>>>(RES2, ln2_w, ln2_b, HBF);

  // MLP in 4 row-chunks of 4096 (keeps gelu buffer at 32MB)
  for (int c = 0; c < 4; ++c) {
    const long ro = (long)c * 4096;
    gemm_f16<EPI_GELU><<<dim3(32, MLPD / 128), 256, 0, stream>>>(
        HBF + ro * DIM, W1T, 4096, MLPD, DIM, b1, nullptr, G);
    gemm_f16<EPI_BIAS_RES><<<dim3(32, DIM / 128), 256, 0, stream>>>(
        G, W2T, 4096, DIM, MLPD, b2, RES2 + ro * DIM,
        (float*)d_out + ro * DIM);
  }
}

// Round 2
// 814.685 us; speedup vs baseline: 1.6088x; 1.6088x over previous
//
#include <hip/hip_runtime.h>
#include <hip/hip_bf16.h>

typedef _Float16 f16;
typedef __attribute__((ext_vector_type(8))) _Float16 f16x8;
typedef __attribute__((ext_vector_type(4))) _Float16 f16x4;
typedef __attribute__((ext_vector_type(4))) float f32x4;

#define DIM 1024
#define HEADS 16
#define DHEAD 64
#define MLPD 4096
#define NQ 16384
#define NW 1024
#define MCHUNK 32  // split-K chunks for calc_m (NW/MCHUNK = 32 rows per block)

// ---------------- async global->LDS (16B per lane) ----------------
__device__ __forceinline__ void glds16(const f16* g, f16* l) {
  __builtin_amdgcn_global_load_lds(
      (const __attribute__((address_space(1))) void*)g,
      (__attribute__((address_space(3))) void*)l, 16, 0, 0);
}

// ---------------- LayerNorm(1024) -> f16 ----------------
__global__ __launch_bounds__(256) void ln_f16_k(
    const float* __restrict__ X, const float* __restrict__ w,
    const float* __restrict__ b, f16* __restrict__ O) {
  const int row = blockIdx.x;
  const int t = threadIdx.x;
  const float4 v = ((const float4*)(X + (long)row * DIM))[t];
  float s = v.x + v.y + v.z + v.w;
  float s2 = v.x * v.x + v.y * v.y + v.z * v.z + v.w * v.w;
#pragma unroll
  for (int m = 1; m < 64; m <<= 1) {
    s += __shfl_xor(s, m);
    s2 += __shfl_xor(s2, m);
  }
  __shared__ float ps[4], ps2[4];
  const int lane = t & 63, wid = t >> 6;
  if (lane == 0) { ps[wid] = s; ps2[wid] = s2; }
  __syncthreads();
  s = ps[0] + ps[1] + ps[2] + ps[3];
  s2 = ps2[0] + ps2[1] + ps2[2] + ps2[3];
  const float mu = s * (1.0f / DIM);
  const float inv = rsqrtf(s2 * (1.0f / DIM) - mu * mu + 1e-5f);
  const float4 wv = ((const float4*)w)[t];
  const float4 bv = ((const float4*)b)[t];
  f16x4 o;
  o[0] = (f16)((v.x - mu) * inv * wv.x + bv.x);
  o[1] = (f16)((v.y - mu) * inv * wv.y + bv.y);
  o[2] = (f16)((v.z - mu) * inv * wv.z + bv.z);
  o[3] = (f16)((v.w - mu) * inv * wv.w + bv.w);
  *(f16x4*)(O + (long)row * DIM + t * 4) = o;
}

// ---------------- transpose + cast f32[R][C] -> f16[C][R] ----------------
__global__ __launch_bounds__(256) void tcast_k(const float* __restrict__ X,
                                               f16* __restrict__ O, int R, int C) {
  __shared__ float tile[32][33];
  const int c0 = blockIdx.x * 32, r0 = blockIdx.y * 32;
  const int tx = threadIdx.x, ty = threadIdx.y;  // (32,8)
#pragma unroll
  for (int j = 0; j < 4; ++j)
    tile[ty + j * 8][tx] = X[(long)(r0 + ty + j * 8) * C + c0 + tx];
  __syncthreads();
#pragma unroll
  for (int j = 0; j < 4; ++j)
    O[(long)(c0 + ty + j * 8) * R + r0 + tx] = (f16)tile[tx][ty + j * 8];
}

// ---------------- M_h partials: Mp[h][ch] = sum_{n in chunk} khat^T v ------------
__global__ __launch_bounds__(256) void calc_m_part_k(const f16* __restrict__ kh,
                                                     const f16* __restrict__ v,
                                                     float* __restrict__ Mp) {
  const int h = blockIdx.x, ch = blockIdx.y;
  const int t = threadIdx.x;
  const int d1 = t >> 2;
  const int d2b = (t & 3) * 16;
  float acc[16] = {};
  const int n0 = ch * (NW / MCHUNK);
#pragma unroll 4
  for (int n = n0; n < n0 + NW / MCHUNK; ++n) {
    const float kv = (float)kh[(long)n * DIM + h * DHEAD + d1];
    const f16x8* vp = (const f16x8*)&v[(long)n * DIM + h * DHEAD + d2b];
    const f16x8 v0 = vp[0], v1 = vp[1];
#pragma unroll
    for (int j = 0; j < 8; ++j) acc[j] += kv * (float)v0[j];
#pragma unroll
    for (int j = 0; j < 8; ++j) acc[8 + j] += kv * (float)v1[j];
  }
  float* o = &Mp[((long)(h * MCHUNK + ch)) * 4096 + d1 * 64 + d2b];
#pragma unroll
  for (int j = 0; j < 16; ++j) o[j] = acc[j];
}

__global__ __launch_bounds__(256) void calc_m_reduce_k(const float* __restrict__ Mp,
                                                       float* __restrict__ Mo) {
  const int h = blockIdx.x;
  const int t = threadIdx.x;
#pragma unroll
  for (int e = t; e < 4096; e += 256) {
    float s = 0.f;
#pragma unroll
    for (int c = 0; c < MCHUNK; ++c)
      s += Mp[((long)(h * MCHUNK + c)) * 4096 + e];
    Mo[h * 4096 + e] = s;
  }
}

// ---------------- W_eff^T[j][i] = sum_d M[h(i)][i%64][d] * wo[h*64+d][j] ----------------
__global__ __launch_bounds__(256) void calc_wefft_k(const float* __restrict__ M,
                                                    const float* __restrict__ wo,
                                                    f16* __restrict__ Wt) {
  const int h = blockIdx.x, jt = blockIdx.y;
  const int t = threadIdx.x;
  const int jl = t & 63;
  const int il0 = (t >> 6) * 16;
  const int j = jt * 64 + jl;
  float acc[16] = {};
  for (int d = 0; d < DHEAD; ++d) {
    const float w = wo[(long)(h * DHEAD + d) * DIM + j];
    const float* mrow = &M[h * 4096 + il0 * 64 + d];
#pragma unroll
    for (int r = 0; r < 16; ++r) acc[r] += mrow[r * 64] * w;
  }
#pragma unroll
  for (int r = 0; r < 16; ++r)
    Wt[(long)j * DIM + h * DHEAD + il0 + r] = (f16)acc[r];
}

// ---------------- main GEMM: C[M][N] = A[M][K](f16) @ Bt[N][K](f16)^T + epilogue ----------
// 128x128 tile, BK=32, 256 threads = 4 waves (2x2), mfma_f32_16x16x32_f16.
enum { EPI_F16 = 0, EPI_L2N = 1, EPI_BIAS_RES = 2, EPI_GELU = 3 };

template <int EPI>
__global__ __launch_bounds__(256, 2) void gemm_f16(
    const f16* __restrict__ A, const f16* __restrict__ Bt, int M, int N, int K,
    const float* __restrict__ bias, const float* __restrict__ resid,
    void* __restrict__ out) {
  __shared__ __align__(16) f16 As[128 * 32];
  __shared__ __align__(16) f16 Bs[128 * 32];

  const int tid = threadIdx.x;
  const int lane = tid & 63;
  const int wid = tid >> 6;
  const int wh = wid >> 1, ww = wid & 1;

  // XCD-aware bijective blockIdx swizzle (grid sizes here are all %8==0)
  const int total = gridDim.x * gridDim.y;
  int bm, bn;
  {
    const int orig = blockIdx.y * gridDim.x + blockIdx.x;
    int swz = orig;
    if ((total & 7) == 0) swz = (orig & 7) * (total >> 3) + (orig >> 3);
    bm = swz % gridDim.x;
    bn = swz / gridDim.x;
  }

  // staging: thread t loads 8 f16 at row=t/4 (+64 for 2nd half), k=(t%4)*8
  const int srow = tid >> 2;
  const int sk = (tid & 3) * 8;
  const f16* ag = A + (long)(bm * 128 + srow) * K + sk;
  const f16* bg = Bt + (long)(bn * 128 + srow) * K + sk;
  f16* asd = &As[tid * 8];
  f16* bsd = &Bs[tid * 8];
  const long hstep = (long)64 * K;

  f32x4 acc[4][4] = {};
  const int nk = K >> 5;
  for (int kt = 0; kt < nk; ++kt) {
    if (kt) __syncthreads();
    const long go = (long)kt * 32;
    glds16(ag + go, asd);
    glds16(ag + hstep + go, asd + 2048);
    glds16(bg + go, bsd);
    glds16(bg + hstep + go, bsd + 2048);
    __syncthreads();

    f16x8 af[4], bf[4];
    const int ar = wh * 64 + (lane & 15);
    const int br = ww * 64 + (lane & 15);
    const int ko = (lane >> 4) * 8;
#pragma unroll
    for (int mi = 0; mi < 4; ++mi)
      af[mi] = *(const f16x8*)&As[(ar + mi * 16) * 32 + ko];
#pragma unroll
    for (int nj = 0; nj < 4; ++nj)
      bf[nj] = *(const f16x8*)&Bs[(br + nj * 16) * 32 + ko];
#pragma unroll
    for (int mi = 0; mi < 4; ++mi)
#pragma unroll
      for (int nj = 0; nj < 4; ++nj)
        acc[mi][nj] = __builtin_amdgcn_mfma_f32_16x16x32_f16(af[mi], bf[nj],
                                                             acc[mi][nj], 0, 0, 0);
  }

  // epilogue: D row=(lane>>4)*4+i, col=lane&15 within each 16x16 frag
  const int r0 = bm * 128 + wh * 64;
  const int c0 = bn * 128 + ww * 64;
  const int lr = (lane >> 4) * 4;
  const int lc = lane & 15;

#pragma unroll
  for (int mi = 0; mi < 4; ++mi) {
#pragma unroll
    for (int i = 0; i < 4; ++i) {
      const long r = r0 + mi * 16 + lr + i;
      if (EPI == EPI_L2N) {
        // wave's 64 cols == one head: l2-normalize this output row over the head
        float ss = 0.f;
#pragma unroll
        for (int nj = 0; nj < 4; ++nj) {
          const float x = acc[mi][nj][i];
          ss += x * x;
        }
        ss += __shfl_xor(ss, 1);
        ss += __shfl_xor(ss, 2);
        ss += __shfl_xor(ss, 4);
        ss += __shfl_xor(ss, 8);
        const float inv = 1.0f / fmaxf(sqrtf(ss), 1e-12f);
#pragma unroll
        for (int nj = 0; nj < 4; ++nj)
          ((f16*)out)[r * N + c0 + nj * 16 + lc] = (f16)(acc[mi][nj][i] * inv);
      } else if (EPI == EPI_F16) {
#pragma unroll
        for (int nj = 0; nj < 4; ++nj)
          ((f16*)out)[r * N + c0 + nj * 16 + lc] = (f16)acc[mi][nj][i];
      } else if (EPI == EPI_BIAS_RES) {
#pragma unroll
        for (int nj = 0; nj < 4; ++nj) {
          const long c = c0 + nj * 16 + lc;
          ((float*)out)[r * N + c] = acc[mi][nj][i] + bias[c] + resid[r * N + c];
        }
      } else {  // EPI_GELU (exact erf)
#pragma unroll
        for (int nj = 0; nj < 4; ++nj) {
          const long c = c0 + nj * 16 + lc;
          const float x = acc[mi][nj][i] + bias[c];
          ((f16*)out)[r * N + c] =
              (f16)(0.5f * x * (1.0f + erff(x * 0.70710678118654752f)));
        }
      }
    }
  }
}

extern "C" void kernel_launch(void* const* d_in, const int* in_sizes, int n_in,
                              void* d_out, int out_size, void* d_ws, size_t ws_size,
                              hipStream_t stream) {
  (void)in_sizes; (void)n_in; (void)out_size;
  const float* queries = (const float*)d_in[0];
  const float* prototypes = (const float*)d_in[1];
  const float* ln1_w = (const float*)d_in[2];
  const float* ln1_b = (const float*)d_in[3];
  const float* wq = (const float*)d_in[4];
  const float* wk = (const float*)d_in[5];
  const float* wv = (const float*)d_in[6];
  const float* wo = (const float*)d_in[7];
  const float* bo = (const float*)d_in[8];
  const float* ln2_w = (const float*)d_in[9];
  const float* ln2_b = (const float*)d_in[10];
  const float* w1 = (const float*)d_in[11];
  const float* b1 = (const float*)d_in[12];
  const float* w2 = (const float*)d_in[13];
  const float* b2 = (const float*)d_in[14];

  char* ws = (char*)d_ws;
  const size_t MB = 1024ull * 1024ull;
  if (ws_size < 192ull * MB) return;  // workspace layout needs 192MB

  // transient region (all dead before MLP; G aliases QN)
  f16* QN = (f16*)(ws + 0);           // 32MB  [16384][1024]
  f16* QHAT = (f16*)(ws + 32 * MB);   // 32MB
  f16* PN = (f16*)(ws + 64 * MB);     // 2MB
  f16* WQT = (f16*)(ws + 66 * MB);    // 2MB
  f16* WKT = (f16*)(ws + 68 * MB);    // 2MB
  f16* WVT = (f16*)(ws + 70 * MB);    // 2MB
  f16* KHAT = (f16*)(ws + 72 * MB);   // 2MB
  f16* VBF = (f16*)(ws + 74 * MB);    // 2MB
  float* Mbuf = (float*)(ws + 76 * MB);  // 256KB
  f16* WEFFT = (f16*)(ws + 77 * MB);  // 2MB
  // persistent region
  float* RES2 = (float*)(ws + 80 * MB);  // 64MB
  f16* HBF = (f16*)(ws + 144 * MB);      // 32MB
  f16* W1T = (f16*)(ws + 176 * MB);      // 8MB [4096][1024]
  f16* W2T = (f16*)(ws + 184 * MB);      // 8MB [1024][4096]
  f16* G = (f16*)(ws + 0);               // 32MB chunk buffer, aliases QN
  // Mpart reuses QN's region too (QN dead after qproj; written before attn gemm)
  float* Mpart = (float*)(ws + 0);       // 16*32*4096*4 = 8MB

  // LN1 + cast
  ln_f16_k<<<NQ, 256, 0, stream>>>(queries, ln1_w, ln1_b, QN);
  ln_f16_k<<<NW, 256, 0, stream>>>(prototypes, ln1_w, ln1_b, PN);
  // weight transpose-casts
  tcast_k<<<dim3(32, 32), dim3(32, 8), 0, stream>>>(wq, WQT, DIM, DIM);
  tcast_k<<<dim3(32, 32), dim3(32, 8), 0, stream>>>(wk, WKT, DIM, DIM);
  tcast_k<<<dim3(32, 32), dim3(32, 8), 0, stream>>>(wv, WVT, DIM, DIM);
  tcast_k<<<dim3(128, 32), dim3(32, 8), 0, stream>>>(w1, W1T, DIM, MLPD);
  tcast_k<<<dim3(32, 128), dim3(32, 8), 0, stream>>>(w2, W2T, MLPD, DIM);

  // projections (+fused per-head l2norm for q,k)
  gemm_f16<EPI_L2N><<<dim3(NQ / 128, DIM / 128), 256, 0, stream>>>(
      QN, WQT, NQ, DIM, DIM, nullptr, nullptr, QHAT);
  gemm_f16<EPI_L2N><<<dim3(NW / 128, DIM / 128), 256, 0, stream>>>(
      PN, WKT, NW, DIM, DIM, nullptr, nullptr, KHAT);
  gemm_f16<EPI_F16><<<dim3(NW / 128, DIM / 128), 256, 0, stream>>>(
      PN, WVT, NW, DIM, DIM, nullptr, nullptr, VBF);

  // attention collapse: M_h = khat^T v (split-K) ; W_eff^T = (blockdiag(M) @ wo)^T
  calc_m_part_k<<<dim3(HEADS, MCHUNK), 256, 0, stream>>>(KHAT, VBF, Mpart);
  calc_m_reduce_k<<<HEADS, 256, 0, stream>>>(Mpart, Mbuf);
  calc_wefft_k<<<dim3(HEADS, 16), 256, 0, stream>>>(Mbuf, wo, WEFFT);

  // attn-out + wo + bias + residual -> RES2 (f32)
  gemm_f16<EPI_BIAS_RES><<<dim3(NQ / 128, DIM / 128), 256, 0, stream>>>(
      QHAT, WEFFT, NQ, DIM, DIM, bo, queries, RES2);

  // LN2
  ln_f16_k<<<NQ, 256, 0, stream>>>(RES2, ln2_w, ln2_b, HBF);

  // MLP in 4 row-chunks of 4096 (keeps gelu buffer at 32MB)
  for (int c = 0; c < 4; ++c) {
    const long ro = (long)c * 4096;
    gemm_f16<EPI_GELU><<<dim3(32, MLPD / 128), 256, 0, stream>>>(
        HBF + ro * DIM, W1T, 4096, MLPD, DIM, b1, nullptr, G);
    gemm_f16<EPI_BIAS_RES><<<dim3(32, DIM / 128), 256, 0, stream>>>(
        G, W2T, 4096, DIM, MLPD, b2, RES2 + ro * DIM,
        (float*)d_out + ro * DIM);
  }
}

// Round 3
// 690.263 us; speedup vs baseline: 1.8988x; 1.1803x over previous
//
#include <hip/hip_runtime.h>
#include <hip/hip_bf16.h>

typedef _Float16 f16;
typedef __attribute__((ext_vector_type(8))) _Float16 f16x8;
typedef __attribute__((ext_vector_type(4))) _Float16 f16x4;
typedef __attribute__((ext_vector_type(4))) float f32x4;

#define DIM 1024
#define HEADS 16
#define DHEAD 64
#define MLPD 4096
#define NQ 16384
#define NW 1024
#define MCHUNK 32  // split-K chunks for calc_m

// ---------------- async global->LDS (16B per lane) ----------------
__device__ __forceinline__ void glds16(const f16* g, f16* l) {
  __builtin_amdgcn_global_load_lds(
      (const __attribute__((address_space(1))) void*)g,
      (__attribute__((address_space(3))) void*)l, 16, 0, 0);
}

// ---------------- LayerNorm(1024): f32 in -> f16 out ----------------
__global__ __launch_bounds__(256) void ln_f16_k(
    const float* __restrict__ X, const float* __restrict__ w,
    const float* __restrict__ b, f16* __restrict__ O) {
  const int row = blockIdx.x;
  const int t = threadIdx.x;
  const float4 v = ((const float4*)(X + (long)row * DIM))[t];
  float s = v.x + v.y + v.z + v.w;
  float s2 = v.x * v.x + v.y * v.y + v.z * v.z + v.w * v.w;
#pragma unroll
  for (int m = 1; m < 64; m <<= 1) {
    s += __shfl_xor(s, m);
    s2 += __shfl_xor(s2, m);
  }
  __shared__ float ps[4], ps2[4];
  const int lane = t & 63, wid = t >> 6;
  if (lane == 0) { ps[wid] = s; ps2[wid] = s2; }
  __syncthreads();
  s = ps[0] + ps[1] + ps[2] + ps[3];
  s2 = ps2[0] + ps2[1] + ps2[2] + ps2[3];
  const float mu = s * (1.0f / DIM);
  const float inv = rsqrtf(s2 * (1.0f / DIM) - mu * mu + 1e-5f);
  const float4 wv = ((const float4*)w)[t];
  const float4 bv = ((const float4*)b)[t];
  f16x4 o;
  o[0] = (f16)((v.x - mu) * inv * wv.x + bv.x);
  o[1] = (f16)((v.y - mu) * inv * wv.y + bv.y);
  o[2] = (f16)((v.z - mu) * inv * wv.z + bv.z);
  o[3] = (f16)((v.w - mu) * inv * wv.w + bv.w);
  *(f16x4*)(O + (long)row * DIM + t * 4) = o;
}

// ---------------- LayerNorm(1024): f16 in -> f16 out ----------------
__global__ __launch_bounds__(256) void ln_f16in_k(
    const f16* __restrict__ X, const float* __restrict__ w,
    const float* __restrict__ b, f16* __restrict__ O) {
  const int row = blockIdx.x;
  const int t = threadIdx.x;
  const f16x4 hv = *(const f16x4*)(X + (long)row * DIM + t * 4);
  const float x0 = (float)hv[0], x1 = (float)hv[1], x2 = (float)hv[2],
              x3 = (float)hv[3];
  float s = x0 + x1 + x2 + x3;
  float s2 = x0 * x0 + x1 * x1 + x2 * x2 + x3 * x3;
#pragma unroll
  for (int m = 1; m < 64; m <<= 1) {
    s += __shfl_xor(s, m);
    s2 += __shfl_xor(s2, m);
  }
  __shared__ float ps[4], ps2[4];
  const int lane = t & 63, wid = t >> 6;
  if (lane == 0) { ps[wid] = s; ps2[wid] = s2; }
  __syncthreads();
  s = ps[0] + ps[1] + ps[2] + ps[3];
  s2 = ps2[0] + ps2[1] + ps2[2] + ps2[3];
  const float mu = s * (1.0f / DIM);
  const float inv = rsqrtf(s2 * (1.0f / DIM) - mu * mu + 1e-5f);
  const float4 wv = ((const float4*)w)[t];
  const float4 bv = ((const float4*)b)[t];
  f16x4 o;
  o[0] = (f16)((x0 - mu) * inv * wv.x + bv.x);
  o[1] = (f16)((x1 - mu) * inv * wv.y + bv.y);
  o[2] = (f16)((x2 - mu) * inv * wv.z + bv.z);
  o[3] = (f16)((x3 - mu) * inv * wv.w + bv.w);
  *(f16x4*)(O + (long)row * DIM + t * 4) = o;
}

// ---------------- transpose + cast f32[R][C] -> f16[C][R] ----------------
__global__ __launch_bounds__(256) void tcast_k(const float* __restrict__ X,
                                               f16* __restrict__ O, int R, int C) {
  __shared__ float tile[32][33];
  const int c0 = blockIdx.x * 32, r0 = blockIdx.y * 32;
  const int tx = threadIdx.x, ty = threadIdx.y;  // (32,8)
#pragma unroll
  for (int j = 0; j < 4; ++j)
    tile[ty + j * 8][tx] = X[(long)(r0 + ty + j * 8) * C + c0 + tx];
  __syncthreads();
#pragma unroll
  for (int j = 0; j < 4; ++j)
    O[(long)(c0 + ty + j * 8) * R + r0 + tx] = (f16)tile[tx][ty + j * 8];
}

// ---------------- M_h partials: Mp[h][ch] = sum_{n in chunk} khat^T v ------------
__global__ __launch_bounds__(256) void calc_m_part_k(const f16* __restrict__ kh,
                                                     const f16* __restrict__ v,
                                                     float* __restrict__ Mp) {
  const int h = blockIdx.x, ch = blockIdx.y;
  const int t = threadIdx.x;
  const int d1 = t >> 2;
  const int d2b = (t & 3) * 16;
  float acc[16] = {};
  const int n0 = ch * (NW / MCHUNK);
#pragma unroll 4
  for (int n = n0; n < n0 + NW / MCHUNK; ++n) {
    const float kv = (float)kh[(long)n * DIM + h * DHEAD + d1];
    const f16x8* vp = (const f16x8*)&v[(long)n * DIM + h * DHEAD + d2b];
    const f16x8 v0 = vp[0], v1 = vp[1];
#pragma unroll
    for (int j = 0; j < 8; ++j) acc[j] += kv * (float)v0[j];
#pragma unroll
    for (int j = 0; j < 8; ++j) acc[8 + j] += kv * (float)v1[j];
  }
  float* o = &Mp[((long)(h * MCHUNK + ch)) * 4096 + d1 * 64 + d2b];
#pragma unroll
  for (int j = 0; j < 16; ++j) o[j] = acc[j];
}

__global__ __launch_bounds__(256) void calc_m_reduce_k(const float* __restrict__ Mp,
                                                       float* __restrict__ Mo) {
  const int h = blockIdx.x;
  const int t = threadIdx.x;
#pragma unroll
  for (int e = t; e < 4096; e += 256) {
    float s = 0.f;
#pragma unroll
    for (int c = 0; c < MCHUNK; ++c)
      s += Mp[((long)(h * MCHUNK + c)) * 4096 + e];
    Mo[h * 4096 + e] = s;
  }
}

// ---------------- W_eff^T[j][i] = sum_d M[h(i)][i%64][d] * wo[h*64+d][j] ----------------
__global__ __launch_bounds__(256) void calc_wefft_k(const float* __restrict__ M,
                                                    const float* __restrict__ wo,
                                                    f16* __restrict__ Wt) {
  const int h = blockIdx.x, jt = blockIdx.y;
  const int t = threadIdx.x;
  const int jl = t & 63;
  const int il0 = (t >> 6) * 16;
  const int j = jt * 64 + jl;
  float acc[16] = {};
  for (int d = 0; d < DHEAD; ++d) {
    const float w = wo[(long)(h * DHEAD + d) * DIM + j];
    const float* mrow = &M[h * 4096 + il0 * 64 + d];
#pragma unroll
    for (int r = 0; r < 16; ++r) acc[r] += mrow[r * 64] * w;
  }
#pragma unroll
  for (int r = 0; r < 16; ++r)
    Wt[(long)j * DIM + h * DHEAD + il0 + r] = (f16)acc[r];
}

// ---------------- main GEMM: C[M][N] = A[M][K](f16) @ Bt[N][K](f16)^T + epilogue ----------
// 128x128 tile, BK=32, 4 waves (2x2), mfma_f32_16x16x32_f16,
// 2-phase double-buffered LDS: STAGE(next) -> compute(cur) -> barrier.
enum {
  EPI_F16 = 0,       // f16 out
  EPI_L2N = 1,       // per-head l2norm, f16 out
  EPI_ATTN = 2,      // f16 out = acc + bias + resid_f32
  EPI_GELU = 3,      // f16 out = gelu(acc + bias)
  EPI_OUT = 4        // f32 out = acc + bias + (float)resid_f16
};

template <int EPI>
__global__ __launch_bounds__(256, 2) void gemm_f16(
    const f16* __restrict__ A, const f16* __restrict__ Bt, int M, int N, int K,
    const float* __restrict__ bias, const void* __restrict__ resid,
    void* __restrict__ out) {
  __shared__ __align__(16) f16 As[2][128 * 32];
  __shared__ __align__(16) f16 Bs[2][128 * 32];

  const int tid = threadIdx.x;
  const int lane = tid & 63;
  const int wid = tid >> 6;
  const int wh = wid >> 1, ww = wid & 1;

  // XCD-aware bijective blockIdx swizzle (grid sizes here are all %8==0)
  const int total = gridDim.x * gridDim.y;
  int bm, bn;
  {
    const int orig = blockIdx.y * gridDim.x + blockIdx.x;
    int swz = orig;
    if ((total & 7) == 0) swz = (orig & 7) * (total >> 3) + (orig >> 3);
    bm = swz % gridDim.x;
    bn = swz / gridDim.x;
  }

  // staging: thread t loads 16B at row=t/4 (+64 for 2nd half), k=(t%4)*8
  const int srow = tid >> 2;
  const int sk = (tid & 3) * 8;
  const f16* ag = A + (long)(bm * 128 + srow) * K + sk;
  const f16* bg = Bt + (long)(bn * 128 + srow) * K + sk;
  const long hstep = (long)64 * K;

  f32x4 acc[4][4] = {};
  const int nk = K >> 5;

  // prologue: stage tile 0 into buf 0
  {
    glds16(ag, &As[0][tid * 8]);
    glds16(ag + hstep, &As[0][tid * 8 + 2048]);
    glds16(bg, &Bs[0][tid * 8]);
    glds16(bg + hstep, &Bs[0][tid * 8 + 2048]);
  }
  __syncthreads();

  int cur = 0;
  const int ar = wh * 64 + (lane & 15);
  const int br = ww * 64 + (lane & 15);
  const int ko = (lane >> 4) * 8;

  for (int kt = 0; kt < nk; ++kt) {
    if (kt + 1 < nk) {  // stage next tile into the other buffer
      const long go = (long)(kt + 1) * 32;
      const int nb = cur ^ 1;
      glds16(ag + go, &As[nb][tid * 8]);
      glds16(ag + hstep + go, &As[nb][tid * 8 + 2048]);
      glds16(bg + go, &Bs[nb][tid * 8]);
      glds16(bg + hstep + go, &Bs[nb][tid * 8 + 2048]);
    }
    f16x8 af[4], bf[4];
#pragma unroll
    for (int mi = 0; mi < 4; ++mi)
      af[mi] = *(const f16x8*)&As[cur][(ar + mi * 16) * 32 + ko];
#pragma unroll
    for (int nj = 0; nj < 4; ++nj)
      bf[nj] = *(const f16x8*)&Bs[cur][(br + nj * 16) * 32 + ko];
#pragma unroll
    for (int mi = 0; mi < 4; ++mi)
#pragma unroll
      for (int nj = 0; nj < 4; ++nj)
        acc[mi][nj] = __builtin_amdgcn_mfma_f32_16x16x32_f16(af[mi], bf[nj],
                                                             acc[mi][nj], 0, 0, 0);
    __syncthreads();  // drains vmcnt(0): next buffer staged; everyone done with cur
    cur ^= 1;
  }

  // epilogue: D row=(lane>>4)*4+i, col=lane&15 within each 16x16 frag
  const int r0 = bm * 128 + wh * 64;
  const int c0 = bn * 128 + ww * 64;
  const int lr = (lane >> 4) * 4;
  const int lc = lane & 15;

#pragma unroll
  for (int mi = 0; mi < 4; ++mi) {
#pragma unroll
    for (int i = 0; i < 4; ++i) {
      const long r = r0 + mi * 16 + lr + i;
      if (EPI == EPI_L2N) {
        float ss = 0.f;
#pragma unroll
        for (int nj = 0; nj < 4; ++nj) {
          const float x = acc[mi][nj][i];
          ss += x * x;
        }
        ss += __shfl_xor(ss, 1);
        ss += __shfl_xor(ss, 2);
        ss += __shfl_xor(ss, 4);
        ss += __shfl_xor(ss, 8);
        const float inv = 1.0f / fmaxf(sqrtf(ss), 1e-12f);
#pragma unroll
        for (int nj = 0; nj < 4; ++nj)
          ((f16*)out)[r * N + c0 + nj * 16 + lc] = (f16)(acc[mi][nj][i] * inv);
      } else if (EPI == EPI_F16) {
#pragma unroll
        for (int nj = 0; nj < 4; ++nj)
          ((f16*)out)[r * N + c0 + nj * 16 + lc] = (f16)acc[mi][nj][i];
      } else if (EPI == EPI_ATTN) {
#pragma unroll
        for (int nj = 0; nj < 4; ++nj) {
          const long c = c0 + nj * 16 + lc;
          ((f16*)out)[r * N + c] =
              (f16)(acc[mi][nj][i] + bias[c] + ((const float*)resid)[r * N + c]);
        }
      } else if (EPI == EPI_GELU) {
#pragma unroll
        for (int nj = 0; nj < 4; ++nj) {
          const long c = c0 + nj * 16 + lc;
          const float x = acc[mi][nj][i] + bias[c];
          ((f16*)out)[r * N + c] =
              (f16)(0.5f * x * (1.0f + erff(x * 0.70710678118654752f)));
        }
      } else {  // EPI_OUT
#pragma unroll
        for (int nj = 0; nj < 4; ++nj) {
          const long c = c0 + nj * 16 + lc;
          ((float*)out)[r * N + c] =
              acc[mi][nj][i] + bias[c] + (float)((const f16*)resid)[r * N + c];
        }
      }
    }
  }
}

extern "C" void kernel_launch(void* const* d_in, const int* in_sizes, int n_in,
                              void* d_out, int out_size, void* d_ws, size_t ws_size,
                              hipStream_t stream) {
  (void)in_sizes; (void)n_in; (void)out_size;
  const float* queries = (const float*)d_in[0];
  const float* prototypes = (const float*)d_in[1];
  const float* ln1_w = (const float*)d_in[2];
  const float* ln1_b = (const float*)d_in[3];
  const float* wq = (const float*)d_in[4];
  const float* wk = (const float*)d_in[5];
  const float* wv = (const float*)d_in[6];
  const float* wo = (const float*)d_in[7];
  const float* bo = (const float*)d_in[8];
  const float* ln2_w = (const float*)d_in[9];
  const float* ln2_b = (const float*)d_in[10];
  const float* w1 = (const float*)d_in[11];
  const float* b1 = (const float*)d_in[12];
  const float* w2 = (const float*)d_in[13];
  const float* b2 = (const float*)d_in[14];

  char* ws = (char*)d_ws;
  const size_t MB = 1024ull * 1024ull;
  if (ws_size < 160ull * MB) return;  // workspace layout needs 160MB

  // transient region
  f16* QN = (f16*)(ws + 0);            // 32MB [16384][1024], dead after qproj
  f16* QHAT = (f16*)(ws + 32 * MB);    // 32MB, dead after attn gemm
  f16* PN = (f16*)(ws + 64 * MB);      // 2MB
  f16* WQT = (f16*)(ws + 66 * MB);     // 2MB
  f16* WKT = (f16*)(ws + 68 * MB);     // 2MB
  f16* WVT = (f16*)(ws + 70 * MB);     // 2MB
  f16* KHAT = (f16*)(ws + 72 * MB);    // 2MB
  f16* VBF = (f16*)(ws + 74 * MB);     // 2MB
  float* Mbuf = (float*)(ws + 76 * MB);   // 256KB
  f16* WEFFT = (f16*)(ws + 77 * MB);   // 2MB
  float* Mpart = (float*)(ws + 0);     // 8MB, aliases QN (QN dead by then)
  // persistent region
  f16* RES2 = (f16*)(ws + 80 * MB);    // 32MB [16384][1024] f16
  f16* HBF = (f16*)(ws + 112 * MB);    // 32MB
  f16* W1T = (f16*)(ws + 144 * MB);    // 8MB [4096][1024]
  f16* W2T = (f16*)(ws + 152 * MB);    // 8MB [1024][4096]
  f16* G = (f16*)(ws + 0);             // 64MB [8192][4096], aliases QN+QHAT

  // LN1 + cast
  ln_f16_k<<<NQ, 256, 0, stream>>>(queries, ln1_w, ln1_b, QN);
  ln_f16_k<<<NW, 256, 0, stream>>>(prototypes, ln1_w, ln1_b, PN);
  // weight transpose-casts
  tcast_k<<<dim3(32, 32), dim3(32, 8), 0, stream>>>(wq, WQT, DIM, DIM);
  tcast_k<<<dim3(32, 32), dim3(32, 8), 0, stream>>>(wk, WKT, DIM, DIM);
  tcast_k<<<dim3(32, 32), dim3(32, 8), 0, stream>>>(wv, WVT, DIM, DIM);
  tcast_k<<<dim3(128, 32), dim3(32, 8), 0, stream>>>(w1, W1T, DIM, MLPD);
  tcast_k<<<dim3(32, 128), dim3(32, 8), 0, stream>>>(w2, W2T, MLPD, DIM);

  // projections (+fused per-head l2norm for q,k)
  gemm_f16<EPI_L2N><<<dim3(NQ / 128, DIM / 128), 256, 0, stream>>>(
      QN, WQT, NQ, DIM, DIM, nullptr, nullptr, QHAT);
  gemm_f16<EPI_L2N><<<dim3(NW / 128, DIM / 128), 256, 0, stream>>>(
      PN, WKT, NW, DIM, DIM, nullptr, nullptr, KHAT);
  gemm_f16<EPI_F16><<<dim3(NW / 128, DIM / 128), 256, 0, stream>>>(
      PN, WVT, NW, DIM, DIM, nullptr, nullptr, VBF);

  // attention collapse: M_h = khat^T v (split-K) ; W_eff^T = (blockdiag(M) @ wo)^T
  calc_m_part_k<<<dim3(HEADS, MCHUNK), 256, 0, stream>>>(KHAT, VBF, Mpart);
  calc_m_reduce_k<<<HEADS, 256, 0, stream>>>(Mpart, Mbuf);
  calc_wefft_k<<<dim3(HEADS, 16), 256, 0, stream>>>(Mbuf, wo, WEFFT);

  // attn-out + wo + bias + residual -> RES2 (f16)
  gemm_f16<EPI_ATTN><<<dim3(NQ / 128, DIM / 128), 256, 0, stream>>>(
      QHAT, WEFFT, NQ, DIM, DIM, bo, queries, RES2);

  // LN2 (f16 in)
  ln_f16in_k<<<NQ, 256, 0, stream>>>(RES2, ln2_w, ln2_b, HBF);

  // MLP in 2 row-chunks of 8192
  for (int c = 0; c < 2; ++c) {
    const long ro = (long)c * 8192;
    gemm_f16<EPI_GELU><<<dim3(64, MLPD / 128), 256, 0, stream>>>(
        HBF + ro * DIM, W1T, 8192, MLPD, DIM, b1, nullptr, G);
    gemm_f16<EPI_OUT><<<dim3(64, DIM / 128), 256, 0, stream>>>(
        G, W2T, 8192, DIM, MLPD, b2, RES2 + ro * DIM,
        (float*)d_out + ro * DIM);
  }
}